// Round 5
// baseline (141.572 us; speedup 1.0000x reference)
//
#include <hip/hip_runtime.h>
#include <cstddef>

// ----------------------------------------------------------------------------
// AttentionFusion round 4: same structure as round 3 (7 kernels: prep merged,
// LN merged, coalesced pyt epilogue) but the scores inner loop uses inline-asm
// v_pk_{add,max,fma}_f16 on unsigned pairs (ROCm header lacks __hmax2).
// ----------------------------------------------------------------------------

#define D_  768
#define HD_ 768
#define NH_ 4
#define B_  4
#define T1_ 128
#define T2_ 128
#define M_  (B_*T1_)
#define LN_EPS_ 1e-5f

typedef unsigned short u16;
typedef unsigned int u32;
typedef _Float16 f16;
typedef _Float16 f16x2 __attribute__((ext_vector_type(2)));
typedef __bf16 bf16x8 __attribute__((ext_vector_type(8)));
typedef float f32x4 __attribute__((ext_vector_type(4)));

__device__ __forceinline__ u16 f2bf(float f) {
    union { float f; unsigned int u; } v; v.f = f;
    unsigned int u = v.u + (0x7FFFu + ((v.u >> 16) & 1u));
    return (u16)(u >> 16);
}
__device__ __forceinline__ u16 f16bits(f16 h) {
    return __builtin_bit_cast(unsigned short, h);
}
__device__ __forceinline__ u32 splat2(u16 h) {
    return (u32)h * 0x10001u;
}
// packed f16 ops, guaranteed VOP3P encoding
__device__ __forceinline__ u32 pk_add(u32 a, u32 b) {
    u32 d; asm("v_pk_add_f16 %0, %1, %2" : "=v"(d) : "v"(a), "v"(b)); return d;
}
__device__ __forceinline__ u32 pk_max0(u32 a) {
    u32 d; asm("v_pk_max_f16 %0, %1, %2" : "=v"(d) : "v"(a), "v"(0u)); return d;
}
__device__ __forceinline__ u32 pk_fma(u32 a, u32 b, u32 c) {
    u32 d; asm("v_pk_fma_f16 %0, %1, %2, %3" : "=v"(d) : "v"(a), "v"(b), "v"(c)); return d;
}
__device__ __forceinline__ float lo_f(u32 u) {
    f16x2 v = __builtin_bit_cast(f16x2, u); return (float)v.x;
}
__device__ __forceinline__ float hi_f(u32 u) {
    f16x2 v = __builtin_bit_cast(f16x2, u); return (float)v.y;
}

// ---------------- bf16 MFMA GEMM: C[M,N] = A[M,K] @ Bt[N,K]^T + bias --------
// MODE: 0 = f32 rows, 1 = bf16 rows, 2 = f16 rows, 3 = f16 transposed (py_t)
template<bool RELU, int MODE>
__device__ __forceinline__ void gemm_mfma_body(
    const u16* __restrict__ A, int lda,
    const u16* __restrict__ Bt, int ldb,
    const float* __restrict__ bias,
    void* __restrict__ C, int ldc, int K, int m0, int n0)
{
    __shared__ __align__(16) u16 As[64][40];
    __shared__ __align__(16) u16 Bs[64][40];
    __shared__ u16 Ts[MODE == 3 ? 64 : 1][MODE == 3 ? 68 : 1];  // transpose buf

    const int tid = threadIdx.x;
    const int row = tid >> 2;
    const int kq  = (tid & 3) << 3;
    const int lane = tid & 63;
    const int w  = tid >> 6;
    const int wr = (w >> 1) << 5;
    const int wc = (w & 1) << 5;
    const int l16 = lane & 15;
    const int lk8 = (lane >> 4) << 3;
    const int r4  = (lane >> 4) << 2;

    const u16* aptr = A + (size_t)(m0 + row) * lda + kq;
    const u16* bptr = Bt + (size_t)(n0 + row) * ldb + kq;

    f32x4 acc00 = {0.f,0.f,0.f,0.f}, acc01 = {0.f,0.f,0.f,0.f};
    f32x4 acc10 = {0.f,0.f,0.f,0.f}, acc11 = {0.f,0.f,0.f,0.f};

    uint4 a_nxt = *(const uint4*)aptr;
    uint4 b_nxt = *(const uint4*)bptr;

    for (int k0 = 0; k0 < K; k0 += 32) {
        __syncthreads();
        *(uint4*)&As[row][kq] = a_nxt;
        *(uint4*)&Bs[row][kq] = b_nxt;
        if (k0 + 32 < K) {
            a_nxt = *(const uint4*)(aptr + k0 + 32);
            b_nxt = *(const uint4*)(bptr + k0 + 32);
        }
        __syncthreads();
        bf16x8 af0 = *(const bf16x8*)&As[wr + l16][lk8];
        bf16x8 af1 = *(const bf16x8*)&As[wr + 16 + l16][lk8];
        bf16x8 bf0 = *(const bf16x8*)&Bs[wc + l16][lk8];
        bf16x8 bf1 = *(const bf16x8*)&Bs[wc + 16 + l16][lk8];
        acc00 = __builtin_amdgcn_mfma_f32_16x16x32_bf16(af0, bf0, acc00, 0, 0, 0);
        acc01 = __builtin_amdgcn_mfma_f32_16x16x32_bf16(af0, bf1, acc01, 0, 0, 0);
        acc10 = __builtin_amdgcn_mfma_f32_16x16x32_bf16(af1, bf0, acc10, 0, 0, 0);
        acc11 = __builtin_amdgcn_mfma_f32_16x16x32_bf16(af1, bf1, acc11, 0, 0, 0);
    }

#define EPI_FRAG(ACC, MF, NF)                                                  \
    {                                                                          \
        const int gcol = n0 + wc + (NF)*16 + l16;                              \
        const float bv = bias ? bias[gcol] : 0.f;                              \
        float v_[4];                                                           \
        _Pragma("unroll")                                                      \
        for (int r = 0; r < 4; r++) {                                          \
            float v = ACC[r] + bv;                                             \
            if (RELU) v = fmaxf(v, 0.f);                                       \
            v_[r] = v;                                                         \
        }                                                                      \
        const int lr0 = wr + (MF)*16 + r4;                                     \
        if (MODE == 3) {                                                       \
            const int lc = wc + (NF)*16 + l16;                                 \
            _Pragma("unroll")                                                  \
            for (int r = 0; r < 4; r++) Ts[lc][lr0 + r] = f16bits((f16)v_[r]); \
        } else {                                                               \
            _Pragma("unroll")                                                  \
            for (int r = 0; r < 4; r++) {                                      \
                const size_t off = (size_t)(m0 + lr0 + r) * ldc + gcol;        \
                if (MODE == 0) ((float*)C)[off] = v_[r];                       \
                else if (MODE == 1) ((u16*)C)[off] = f2bf(v_[r]);              \
                else ((u16*)C)[off] = f16bits((f16)v_[r]);                     \
            }                                                                  \
        }                                                                      \
    }
    EPI_FRAG(acc00, 0, 0) EPI_FRAG(acc01, 0, 1)
    EPI_FRAG(acc10, 1, 0) EPI_FRAG(acc11, 1, 1)
#undef EPI_FRAG

    if (MODE == 3) {
        // coalesced write of the 64(s) x 64(h) tile into pyt[b][h][s]
        __syncthreads();
        u16* cb = (u16*)C + (size_t)(m0 >> 7) * (768 * 128) + (m0 & 127);
#pragma unroll
        for (int u = 0; u < 4; u++) {
            const int i = tid + u * 256;          // 0..1023 units of 4 s
            const int hl = i >> 4;                // 0..63
            const int s4 = (i & 15) << 2;         // 0..60
            ushort4 o;
            o.x = Ts[hl][s4 + 0]; o.y = Ts[hl][s4 + 1];
            o.z = Ts[hl][s4 + 2]; o.w = Ts[hl][s4 + 3];
            *(ushort4*)(cb + (size_t)(n0 + hl) * 128 + s4) = o;
        }
    }
}

// ---------------------------------------------------------------------------
// K0: merged prep. blocks [0,768): convert inputs fp32->bf16.
// blocks [768,8832): 32x32 transpose+convert tiles of W1/Wf1/Wf2.
// ---------------------------------------------------------------------------
__global__ __launch_bounds__(256) void prep_kernel(
    const float* __restrict__ speech, const float* __restrict__ phon,
    const float* __restrict__ W1, const float* __restrict__ Wf1,
    const float* __restrict__ Wf2,
    u16* __restrict__ spb, u16* __restrict__ phb,
    u16* __restrict__ w1t, u16* __restrict__ wf1t, u16* __restrict__ wf2t)
{
    const int tid = threadIdx.x;
    int bid = blockIdx.x;
    if (bid < 768) {
        const bool isp = bid < 384;
        const float* in = isp ? speech : phon;
        u16* outb = isp ? spb : phb;
        const int i = ((isp ? bid : bid - 384) * 256 + tid) * 4;
        float4 v = *(const float4*)(in + i);
        ushort4 o;
        o.x = f2bf(v.x); o.y = f2bf(v.y); o.z = f2bf(v.z); o.w = f2bf(v.w);
        *(ushort4*)(outb + i) = o;
        return;
    }
    bid -= 768;
    const float* in; u16* outp; int tx, ty;
    if (bid < 4608) {
        const int z = bid / 1152, r = bid % 1152;
        tx = r % 24; ty = r / 24;
        in = W1 + (size_t)z * 1536 * 768; outp = w1t + (size_t)z * 768 * 1536;
    } else if (bid < 6912) {
        const int r = bid - 4608;
        tx = r % 48; ty = r / 48;
        in = Wf1; outp = wf1t;
    } else {
        const int r = bid - 6912;
        tx = r % 24; ty = r / 24;
        in = Wf2; outp = wf2t;
    }
    const int C = (bid >= 4608 && bid < 6912) ? 1536 : 768;
    const int c0 = tx * 32, r0 = ty * 32;
    __shared__ float tile[32][33];
    const int tr = tid >> 3, tc = (tid & 7) << 2;
    float4 v = *(const float4*)(in + (size_t)(r0 + tr) * C + c0 + tc);
    tile[tr][tc] = v.x; tile[tr][tc + 1] = v.y; tile[tr][tc + 2] = v.z; tile[tr][tc + 3] = v.w;
    __syncthreads();
    ushort4 o;
    o.x = f2bf(tile[tc + 0][tr]); o.y = f2bf(tile[tc + 1][tr]);
    o.z = f2bf(tile[tc + 2][tr]); o.w = f2bf(tile[tc + 3][tr]);
    *(ushort4*)(outp + (size_t)(c0 + tr) * 1536 + r0 + tc) = o;
}

// K1: 8 GEMMs -> sx (b1 folded, f16 rows) and py_t (f16 transposed). grid (12,8,8)
__global__ __launch_bounds__(256) void gemm_sxpy_kernel(
    const u16* __restrict__ sp, const u16* __restrict__ ph,
    const u16* __restrict__ w1t, const float* __restrict__ b1,
    u16* __restrict__ sxf, u16* __restrict__ pyt)
{
    const int z = blockIdx.z;
    const int n = z & 3;
    const bool ispy = z >= 4;
    const u16* Bt = w1t + (size_t)n * 768 * 1536 + (ispy ? 768 : 0);
    if (!ispy) {
        gemm_mfma_body<false, 2>(sp, 768, Bt, 1536, b1 + n * HD_,
                                 sxf + (size_t)n * M_ * HD_, HD_, 768,
                                 blockIdx.y * 64, blockIdx.x * 64);
    } else {
        gemm_mfma_body<false, 3>(ph, 768, Bt, 1536, nullptr,
                                 pyt + (size_t)n * 4 * 768 * 128, 0, 768,
                                 blockIdx.y * 64, blockIdx.x * 64);
    }
}

template<bool RELU, int MODE>
__global__ __launch_bounds__(256) void gemm_mfma_kernel(
    const u16* __restrict__ A, int lda,
    const u16* __restrict__ Bt, int ldb,
    const float* __restrict__ bias,
    void* __restrict__ C, int ldc, int K)
{
    gemm_mfma_body<RELU, MODE>(A, lda, Bt, ldb, bias, C, ldc, K,
                               blockIdx.y * 64, blockIdx.x * 64);
}

// ---------------------------------------------------------------------------
// K2: packed-f16 (inline-asm v_pk_*) s-across-lanes scores + softmax.
// grid 256 = (n, b, t8): 4 waves x 2 t-rows each, 128 s as 2 per lane.
// ---------------------------------------------------------------------------
__global__ __launch_bounds__(256) void scores_softmax_kernel(
    const u16* __restrict__ sxf,     // f16 [n][512][768]
    const u16* __restrict__ pyt,     // f16 [n][b][768][128]
    const float* __restrict__ w2,    // f32 [n][768]
    float* __restrict__ probs)       // f32 [n][512][128], 0.25-scaled
{
    const int bid = blockIdx.x;
    const int n = bid >> 6, b = (bid >> 4) & 3, t0 = (bid & 15) * 8;
    const int tid = threadIdx.x, lane = tid & 63, w = tid >> 6;

    __shared__ __align__(16) u32 sxs[8][768];   // splatted sx rows, 24KB
    __shared__ __align__(16) u32 w2s[768];      // splatted w2, 3KB

    for (int q = 0; q < 6; q++) {
        const int u = tid + q * 256;
        const int r = u / 192;
        const int h4 = (u % 192) * 4;
        ushort4 v = *(const ushort4*)(sxf + ((size_t)(n * 512 + b * 128 + t0 + r)) * 768 + h4);
        sxs[r][h4 + 0] = splat2(v.x);
        sxs[r][h4 + 1] = splat2(v.y);
        sxs[r][h4 + 2] = splat2(v.z);
        sxs[r][h4 + 3] = splat2(v.w);
    }
    for (int q = 0; q < 3; q++) {
        const int i = tid + q * 256;
        w2s[i] = splat2(f16bits((f16)w2[n * 768 + i]));
    }
    __syncthreads();

    const u32* pypanel = (const u32*)(pyt + ((size_t)((n << 2) | b)) * 768 * 128) + lane;

    float accA0 = 0.f, accA1 = 0.f, accB0 = 0.f, accB1 = 0.f;
    const int rA = 2 * w, rB = 2 * w + 1;

    u32 b0[16], b1[16];
#pragma unroll
    for (int j = 0; j < 16; j++) b0[j] = pypanel[(size_t)j * 64];
#pragma unroll
    for (int j = 0; j < 16; j++) b1[j] = pypanel[(size_t)(16 + j) * 64];

    auto compute = [&](const u32 (&buf)[16], int hbase) {
        u32 aA = 0u, aB = 0u;
#pragma unroll
        for (int j = 0; j < 16; j++) {
            const u32 p = buf[j];
            const u32 wj = w2s[hbase + j];
            aA = pk_fma(pk_max0(pk_add(sxs[rA][hbase + j], p)), wj, aA);
            aB = pk_fma(pk_max0(pk_add(sxs[rB][hbase + j], p)), wj, aB);
        }
        accA0 += lo_f(aA); accA1 += hi_f(aA);
        accB0 += lo_f(aB); accB1 += hi_f(aB);
    };

    for (int hc = 0; hc < 768; hc += 32) {
        compute(b0, hc);
        if (hc + 32 < 768) {
#pragma unroll
            for (int j = 0; j < 16; j++) b0[j] = pypanel[(size_t)(hc + 32 + j) * 64];
        }
        compute(b1, hc + 16);
        if (hc + 48 < 768) {
#pragma unroll
            for (int j = 0; j < 16; j++) b1[j] = pypanel[(size_t)(hc + 48 + j) * 64];
        }
    }

#pragma unroll
    for (int which = 0; which < 2; which++) {
        const float s0 = which ? accB0 : accA0;
        const float s1 = which ? accB1 : accA1;
        const int t = t0 + 2 * w + which;
        float mx = fmaxf(s0, s1);
#pragma unroll
        for (int off = 32; off; off >>= 1) mx = fmaxf(mx, __shfl_xor(mx, off, 64));
        const float e0 = expf(s0 - mx), e1 = expf(s1 - mx);
        float sm = e0 + e1;
#pragma unroll
        for (int off = 32; off; off >>= 1) sm += __shfl_xor(sm, off, 64);
        const float inv = 0.25f / sm;
        float2 pr; pr.x = e0 * inv; pr.y = e1 * inv;
        *(float2*)&probs[((size_t)(n * 512 + b * 128 + t)) * 128 + 2 * lane] = pr;
    }
}

// K3: attn = sum_n probs; context = attn @ phoneme; fused = [speech, ctx] bf16.
__global__ __launch_bounds__(256) void context_fused_kernel(
    const float* __restrict__ probs, const float* __restrict__ phon,
    const float* __restrict__ speech, u16* __restrict__ fused)
{
    const int m = blockIdx.x;
    const int b = m >> 7;
    const int tid = threadIdx.x;
    __shared__ float attn[T2_];
    if (tid < T2_) {
        float a = 0.f;
#pragma unroll
        for (int n = 0; n < NH_; n++)
            a += probs[(size_t)(n * M_ + m) * T2_ + tid];
        attn[tid] = a;
    }
    __syncthreads();
    const float* ph = phon + (size_t)b * T2_ * D_;
#pragma unroll
    for (int j = 0; j < 3; j++) {
        const int d = tid + 256 * j;
        float acc = 0.f;
#pragma unroll 8
        for (int s = 0; s < T2_; s++)
            acc = fmaf(attn[s], ph[(size_t)s * D_ + d], acc);
        fused[(size_t)m * (2 * D_) + d] = f2bf(speech[(size_t)m * D_ + d]);
        fused[(size_t)m * (2 * D_) + D_ + d] = f2bf(acc);
    }
}

// K6: fused LN stats + time-mean. grid 4 blocks (one per b), 256 threads.
__global__ __launch_bounds__(256) void ln_fused_kernel(
    const float* __restrict__ x, const float* __restrict__ g,
    const float* __restrict__ lb, float* __restrict__ out)
{
    const int b = blockIdx.x, tid = threadIdx.x, lane = tid & 63, w = tid >> 6;
    __shared__ float rs[T1_];
    __shared__ float Sred[4];

    float prsum = 0.f;
    for (int i = 0; i < 32; i++) {
        const int row = w * 32 + i;
        const float4* x4 = (const float4*)(x + ((size_t)(b * T1_ + row)) * D_);
        float s = 0.f, ss = 0.f;
#pragma unroll
        for (int j = 0; j < 3; j++) {
            float4 v = x4[j * 64 + lane];
            s += v.x + v.y + v.z + v.w;
            ss += v.x * v.x + v.y * v.y + v.z * v.z + v.w * v.w;
        }
#pragma unroll
        for (int off = 32; off; off >>= 1) {
            s += __shfl_xor(s, off, 64);
            ss += __shfl_xor(ss, off, 64);
        }
        if (lane == 0) {
            const float mu = s * (1.f / D_);
            const float var = ss * (1.f / D_) - mu * mu;
            const float r = rsqrtf(var + LN_EPS_);
            rs[row] = r;
            prsum += mu * r;
        }
    }
    if (lane == 0) Sred[w] = prsum;
    __syncthreads();
    const float S = Sred[0] + Sred[1] + Sred[2] + Sred[3];
    const float* xb = x + (size_t)b * T1_ * D_;
#pragma unroll
    for (int j = 0; j < 3; j++) {
        const int d = tid + 256 * j;
        float acc = 0.f;
#pragma unroll 8
        for (int t = 0; t < T1_; t++)
            acc = fmaf(xb[(size_t)t * D_ + d], rs[t], acc);
        out[b * D_ + d] = g[d] * (acc - S) * (1.f / T1_) + lb[d];
    }
}

extern "C" void kernel_launch(void* const* d_in, const int* in_sizes, int n_in,
                              void* d_out, int out_size, void* d_ws, size_t ws_size,
                              hipStream_t stream)
{
    const float* speech = (const float*)d_in[0];
    const float* phon   = (const float*)d_in[1];
    const float* W1     = (const float*)d_in[2];
    const float* b1     = (const float*)d_in[3];
    const float* w2     = (const float*)d_in[4];
    // d_in[5] = b2: softmax-invariant, unused
    const float* Wf1    = (const float*)d_in[6];
    const float* bf1    = (const float*)d_in[7];
    const float* Wf2    = (const float*)d_in[8];
    const float* bf2    = (const float*)d_in[9];
    const float* ln_g   = (const float*)d_in[10];
    const float* ln_b   = (const float*)d_in[11];
    float* out = (float*)d_out;

    char* w = (char*)d_ws;
    auto alloc = [&](size_t bytes) { char* p = w; w += (bytes + 1023) & ~(size_t)1023; return p; };
    u16* sp_bf  = (u16*)alloc((size_t)M_ * D_ * 2);
    u16* ph_bf  = (u16*)alloc((size_t)M_ * D_ * 2);
    u16* w1t    = (u16*)alloc((size_t)NH_ * 768 * 1536 * 2);
    u16* wf1t   = (u16*)alloc((size_t)1536 * 1536 * 2);
    u16* wf2t   = (u16*)alloc((size_t)768 * 1536 * 2);
    u16* sxf    = (u16*)alloc((size_t)NH_ * M_ * HD_ * 2);        // f16
    u16* pyt    = (u16*)alloc((size_t)NH_ * B_ * 768 * 128 * 2);  // f16 transposed
    float* probs  = (float*)alloc((size_t)NH_ * M_ * T2_ * 4);
    u16* fusedb = (u16*)alloc((size_t)M_ * 2 * D_ * 2);
    u16* hbuf   = (u16*)alloc((size_t)M_ * 2 * HD_ * 2);
    float* outpre = (float*)alloc((size_t)M_ * D_ * 4);

    hipLaunchKernelGGL(prep_kernel, dim3(8832), dim3(256), 0, stream,
                       speech, phon, W1, Wf1, Wf2, sp_bf, ph_bf, w1t, wf1t, wf2t);
    hipLaunchKernelGGL(gemm_sxpy_kernel, dim3(HD_ / 64, M_ / 64, 8), dim3(256), 0, stream,
                       sp_bf, ph_bf, w1t, b1, sxf, pyt);
    hipLaunchKernelGGL(scores_softmax_kernel, dim3(256), dim3(256), 0, stream,
                       sxf, pyt, w2, probs);
    hipLaunchKernelGGL(context_fused_kernel, dim3(M_), dim3(256), 0, stream,
                       probs, phon, speech, fusedb);
    hipLaunchKernelGGL((gemm_mfma_kernel<true, 1>), dim3(2 * HD_ / 64, M_ / 64), dim3(256), 0, stream,
                       fusedb, 2 * D_, wf1t, 1536, bf1, hbuf, 2 * HD_, 2 * D_);
    hipLaunchKernelGGL((gemm_mfma_kernel<false, 0>), dim3(D_ / 64, M_ / 64), dim3(256), 0, stream,
                       hbuf, 2 * HD_, wf2t, 1536, bf2, outpre, D_, 2 * HD_);
    hipLaunchKernelGGL(ln_fused_kernel, dim3(B_), dim3(256), 0, stream,
                       outpre, ln_g, ln_b, out);
}